// Round 12
// baseline (299.916 us; speedup 1.0000x reference)
//
#include <hip/hip_runtime.h>
#include <cstddef>
#include <cstdint>

#define BATCH   8
#define SEQ     1024
#define DMODEL  1024
#define NHEADS  16
#define DKH     64
#define NE      (BATCH*SEQ*DMODEL)     // 8388608
#define WE      (DMODEL*DMODEL)        // 1048576
#define WE4     (WE/4)                 // 262144

typedef __attribute__((ext_vector_type(8))) short bf16x8;
typedef __attribute__((ext_vector_type(4))) short s16x4;
typedef __attribute__((ext_vector_type(4))) float f32x4;

#define MFMA16(a,b,c) __builtin_amdgcn_mfma_f32_16x16x32_bf16(a,b,c,0,0,0)

__device__ __forceinline__ unsigned short f2bf(float f) {
    uint32_t u = __float_as_uint(f);
    u += 0x7fffu + ((u >> 16) & 1u);          // round-to-nearest-even
    return (unsigned short)(u >> 16);
}
__device__ __forceinline__ float bf2f(unsigned short s) {
    return __uint_as_float(((uint32_t)s) << 16);
}

// async global->LDS, 16B per lane, dest = wave-uniform base + lane*16
__device__ __forceinline__ void gload16(const void* g, void* l) {
    __builtin_amdgcn_global_load_lds(
        (const __attribute__((address_space(1))) void*)g,
        (__attribute__((address_space(3))) void*)l, 16, 0, 0);
}

// ---------------------------------------------------------------------------
// Weights-only conversion (q/k/v conversion is fused into the proj GEMM).
// ---------------------------------------------------------------------------
__global__ void cvt_w(const float* __restrict__ wq, const float* __restrict__ wo,
                      unsigned short* __restrict__ wqh, unsigned short* __restrict__ woh)
{
    const int i = blockIdx.x * blockDim.x + threadIdx.x;
    const float* src; unsigned short* dst; int j;
    if (i < WE4) { src = wq; dst = wqh; j = i; }
    else         { src = wo; dst = woh; j = i - WE4; }
    const f32x4 x = ((const f32x4*)src)[j];
    s16x4 h4;
    #pragma unroll
    for (int e = 0; e < 4; ++e) h4[e] = (short)f2bf(x[e]);
    ((s16x4*)dst)[j] = h4;
}

// ---------------------------------------------------------------------------
// MFMA GEMM: C = A(MxK) * W^T + bias. 128x128 tile, ROUND 12: BK=64
// (32 MFMA + 16 ds_reads per barrier window — covers the prefetch drain;
// barrier count halved 32->16). LDS 64 KiB, 2 blocks/CU.
// Swizzle invariant (both paths): LDS[r][s'] = glb[r][s' ^ (r&7)], 8 slots.
// W (and bf16 A) staged via global_load_lds with pre-swizzled source slot
// gs = (lane&7)^((lane>>3)&7); f32 A (OUTMODE 3) reg-staged + converted.
// 1D grid, bijective XCD-chunked swizzle. K-chunk order identical to BK=32
// version -> bit-identical results.
// OUTMODE 3: fused q/k/v projection. OUTMODE 2: out-proj, NT f32 stores.
// ---------------------------------------------------------------------------
#define GBM 128
#define GBN 128
#define GBK 64

template<int OUTMODE>
__global__ __launch_bounds__(256, 2)
void gemm_mfma(const float* __restrict__ Aq, const float* __restrict__ Ak,
               const float* __restrict__ Av, const unsigned short* __restrict__ Ab,
               const unsigned short* __restrict__ Whi, const float* __restrict__ bias,
               unsigned short* __restrict__ Ohi, unsigned short* __restrict__ Ovt,
               float* __restrict__ Of)
{
    __shared__ unsigned short sA[2][GBM * GBK];   // 32 KiB
    __shared__ unsigned short sW[2][GBM * GBK];   // 32 KiB

    const int tid = threadIdx.x, lane = tid & 63, wid = tid >> 6;
    const int cpx = gridDim.x >> 3;
    const int L = (blockIdx.x & 7) * cpx + (blockIdx.x >> 3);
    const int n0 = (L & 7) * GBN, m0 = (L >> 3) * GBM;
    const int wm = (wid >> 1) * 64, wn = (wid & 1) * 64;
    const int lo = lane & 15, hi4 = lane >> 4;

    // gload staging: call c (0..3): rows wid*32 + c*8 + (lane>>3), slot lane&7
    const int gs = (lane & 7) ^ ((lane >> 3) & 7);      // pre-swizzled source slot
    const int grow = wid * 32 + (lane >> 3);
    const unsigned short* wSrc = &Whi[(size_t)(n0 + grow) * DMODEL + gs * 8];
    const unsigned short* aSrcB = (OUTMODE == 2) ? &Ab[(size_t)(m0 + grow) * DMODEL + gs * 8] : nullptr;

    // OUTMODE 3 reg-staged A: thread t -> row t>>1, 4 slots from (t&1)*4
    const int seg = (OUTMODE == 3) ? (m0 >> 13) : 0;
    const float* Af = (OUTMODE == 3) ? (seg == 0 ? Aq : (seg == 1 ? Ak : Av)) : nullptr;
    const int mloc = m0 & 8191;
    const int arow = tid >> 1;
    const int asb  = (tid & 1) * 4;
    const int akey = arow & 7;
    const float* aF = (OUTMODE == 3) ? &Af[(size_t)(mloc + arow) * DMODEL + asb * 8] : nullptr;

    f32x4 acc[4][4] = {};
    f32x4 par[8];

    // ---- prologue: stage k-tile 0 into buf 0 ----
    if (OUTMODE == 3) {
        #pragma unroll
        for (int v = 0; v < 8; ++v) par[v] = *(const f32x4*)(aF + v * 4);
        #pragma unroll
        for (int s = 0; s < 4; ++s) {
            bf16x8 h8;
            #pragma unroll
            for (int e = 0; e < 4; ++e) {
                h8[e]     = (short)f2bf(par[2 * s][e]);
                h8[4 + e] = (short)f2bf(par[2 * s + 1][e]);
            }
            *(bf16x8*)&sA[0][arow * GBK + ((asb + s) ^ akey) * 8] = h8;
        }
    } else {
        #pragma unroll
        for (int c = 0; c < 4; ++c)
            gload16(aSrcB + (size_t)(c * 8) * DMODEL, &sA[0][(wid * 32 + c * 8) * GBK]);
    }
    #pragma unroll
    for (int c = 0; c < 4; ++c)
        gload16(wSrc + (size_t)(c * 8) * DMODEL, &sW[0][(wid * 32 + c * 8) * GBK]);

    for (int kt = 0; kt < DMODEL / GBK; ++kt) {
        __syncthreads();   // buf[kt&1] staged; buf[(kt+1)&1] free
        const int nb = (kt + 1) & 1;
        if (kt + 1 < DMODEL / GBK) {
            const int kn = (kt + 1) * GBK;
            if (OUTMODE == 3) {
                #pragma unroll
                for (int v = 0; v < 8; ++v) par[v] = *(const f32x4*)(aF + kn + v * 4);
            } else {
                #pragma unroll
                for (int c = 0; c < 4; ++c)
                    gload16(aSrcB + kn + (size_t)(c * 8) * DMODEL, &sA[nb][(wid * 32 + c * 8) * GBK]);
            }
            #pragma unroll
            for (int c = 0; c < 4; ++c)
                gload16(wSrc + kn + (size_t)(c * 8) * DMODEL, &sW[nb][(wid * 32 + c * 8) * GBK]);
        }

        const unsigned short* aB = &sA[kt & 1][0];
        const unsigned short* wB = &sW[kt & 1][0];
        const int fkey = lo & 7;
        #pragma unroll
        for (int ks = 0; ks < 2; ++ks) {
            bf16x8 ah[4], bh_[4];
            #pragma unroll
            for (int m = 0; m < 4; ++m)
                ah[m] = *(const bf16x8*)&aB[(wm + m * 16 + lo) * GBK + (((ks << 2) + hi4) ^ fkey) * 8];
            #pragma unroll
            for (int n = 0; n < 4; ++n)
                bh_[n] = *(const bf16x8*)&wB[(wn + n * 16 + lo) * GBK + (((ks << 2) + hi4) ^ fkey) * 8];
            #pragma unroll
            for (int m = 0; m < 4; ++m)
                #pragma unroll
                for (int n = 0; n < 4; ++n)
                    acc[m][n] = MFMA16(ah[m], bh_[n], acc[m][n]);
        }

        // convert + ds_write next A tile (f32 path) after MFMA issue
        if (OUTMODE == 3 && kt + 1 < DMODEL / GBK) {
            #pragma unroll
            for (int s = 0; s < 4; ++s) {
                bf16x8 h8;
                #pragma unroll
                for (int e = 0; e < 4; ++e) {
                    h8[e]     = (short)f2bf(par[2 * s][e]);
                    h8[4 + e] = (short)f2bf(par[2 * s + 1][e]);
                }
                *(bf16x8*)&sA[nb][arow * GBK + ((asb + s) ^ akey) * 8] = h8;
            }
        }
    }

    #pragma unroll
    for (int n = 0; n < 4; ++n) {
        const int col = n0 + wn + n * 16 + lo;
        const float bv = bias[col];
        #pragma unroll
        for (int m = 0; m < 4; ++m) {
            if (OUTMODE == 3 && seg == 2) {
                const int row0 = (m0 + wm + m * 16 + hi4 * 4) & 8191;
                const int b = row0 >> 10, s0_ = row0 & 1023;
                const int h = col >> 6, di = col & 63;
                s16x4 o;
                #pragma unroll
                for (int j = 0; j < 4; ++j) o[j] = (short)f2bf(acc[m][n][j] + bv);
                *(s16x4*)&Ovt[(((size_t)(b * NHEADS + h)) * DKH + di) * SEQ + s0_] = o;
            } else {
                #pragma unroll
                for (int j = 0; j < 4; ++j) {
                    const int row = m0 + wm + m * 16 + hi4 * 4 + j;
                    const float f = acc[m][n][j] + bv;
                    if (OUTMODE == 3) {
                        const int rs = row & 8191;
                        const int b = rs >> 10, s = rs & 1023;
                        const int h = col >> 6, di = col & 63;
                        unsigned short* dst = Ohi + (size_t)seg * NE;
                        dst[(((size_t)(b * NHEADS + h)) * SEQ + s) * DKH + di] = f2bf(f);
                    } else {
                        __builtin_nontemporal_store(f, &Of[(size_t)row * DMODEL + col]);
                    }
                }
            }
        }
    }
}

// ---------------------------------------------------------------------------
// Fused attention (round-10 version, measured best; rounds 10/11 showed it is
// at its effective floor). Two-pass, 1-term bf16 QK^T, fixed-shift softmax.
// Block = (b,h,128 q-rows), 8 waves, 512 threads, LDS 71680 B.
// K/V via global_load_lds DMA (pre-swizzled source, slot' = s ^ (row&7)),
// double-buffered, one barrier per K-tile. sP32 aliases dead sQh. NT p-stores.
// ---------------------------------------------------------------------------
#define ALD 72
#define KTE 4096   // elems per K/V tile buffer (64 rows x 64)

__global__ __launch_bounds__(512, 4)
void attn_fused(const unsigned short* __restrict__ qhi, const unsigned short* __restrict__ khi,
                const unsigned short* __restrict__ vt, const int* __restrict__ mask,
                float* __restrict__ pattn, unsigned short* __restrict__ xb)
{
    __shared__ __align__(16) char smem[71680];
    unsigned short* sQh = (unsigned short*)smem;             // [128*72] (dead after hoist)
    float*          sP32 = (float*)smem;                     // [8][16*68] (pass 2 alias)
    unsigned short* sKh = (unsigned short*)(smem + 34816);   // [2][4096]
    unsigned short* sVt = (unsigned short*)(smem + 51200);   // [2][4096]
    int*            sM  = (int*)(smem + 67584);              // [1024]

    const int blk = blockIdx.x;
    const int idx = blk >> 3;
    const int bh = (blk & 7) * 16 + (idx & 15);
    const int qt = idx >> 4;                   // 0..7
    const int b = bh >> 4, h = bh & 15;
    const int q0 = qt * 128;
    const int tid = threadIdx.x, lane = tid & 63, wid = tid >> 6;
    const int lo = lane & 15, hi = lane >> 4;

    const int sr8 = tid >> 3;
    const int sw  = (tid & 7) ^ (sr8 & 7);
    const unsigned short* kSrc = &khi[(size_t)bh * SEQ * DKH + (size_t)sr8 * DKH + sw * 8];
    const unsigned short* vSrc = &vt[(size_t)bh * DKH * SEQ + (size_t)sr8 * SEQ + sw * 8];

    *(int2*)&sM[tid * 2] = *(const int2*)&mask[b * SEQ + tid * 2];
    #pragma unroll
    for (int c = 0; c < 2; ++c) {
        const int id = tid * 2 + c, row = id >> 3, col = (id & 7) * 8;
        *(bf16x8*)&sQh[row * ALD + col] =
            *(const bf16x8*)&qhi[((size_t)bh * SEQ + q0 + row) * DKH + col];
    }
    gload16(kSrc, &sKh[0] + wid * 512);
    __syncthreads();   // Q staged + K tile0 DMA drained

    const int qrow = wid * 16 + lo;            // 0..127
    bf16x8 aqh[2];
    aqh[0] = *(const bf16x8*)&sQh[qrow * ALD + hi * 8];
    aqh[1] = *(const bf16x8*)&sQh[qrow * ALD + 32 + hi * 8];
    int mqr[4];
    #pragma unroll
    for (int j = 0; j < 4; ++j) mqr[j] = sM[q0 + wid * 16 + hi * 4 + j];

    // ================= PASS 1: row sums =================
    float l4[4] = {0.f, 0.f, 0.f, 0.f};
    for (int kt = 0; kt < 16; ++kt) {
        if (kt < 15)
            gload16(kSrc + (size_t)(kt + 1) * 64 * DKH, &sKh[((kt + 1) & 1) * KTE] + wid * 512);
        const unsigned short* kB = &sKh[(kt & 1) * KTE];
        f32x4 acc4[4] = {};
        #pragma unroll
        for (int ks = 0; ks < 2; ++ks)
            #pragma unroll
            for (int n = 0; n < 4; ++n) {
                const int row = n * 16 + lo;
                acc4[n] = MFMA16(aqh[ks],
                    *(const bf16x8*)&kB[row * 64 + (((ks << 2) + hi) ^ (row & 7)) * 8], acc4[n]);
            }
        #pragma unroll
        for (int n = 0; n < 4; ++n) {
            const int mkc = sM[kt * 64 + n * 16 + lo];
            #pragma unroll
            for (int j = 0; j < 4; ++j)
                l4[j] += (mqr[j] && mkc) ? __expf(acc4[n][j] * 0.125f) : 0.f;
        }
        __syncthreads();   // tile kt reads done; tile kt+1 DMA drained
    }
    float rinv[4];
    #pragma unroll
    for (int j = 0; j < 4; ++j) {
        float s = l4[j];
        #pragma unroll
        for (int o = 1; o < 16; o <<= 1) s += __shfl_xor(s, o, 16);
        rinv[j] = (s > 0.f) ? (1.0f / s) : 0.f;
    }

    // ================= PASS 2: p write + PV =================
    f32x4 oacc[4] = {};
    gload16(kSrc, &sKh[0] + wid * 512);
    gload16(vSrc, &sVt[0] + wid * 512);
    __syncthreads();
    for (int kt = 0; kt < 16; ++kt) {
        if (kt < 15) {
            const int nb = ((kt + 1) & 1);
            gload16(kSrc + (size_t)(kt + 1) * 64 * DKH, &sKh[nb * KTE] + wid * 512);
            gload16(vSrc + (kt + 1) * 64,               &sVt[nb * KTE] + wid * 512);
        }
        const unsigned short* kB = &sKh[(kt & 1) * KTE];
        const unsigned short* vB = &sVt[(kt & 1) * KTE];
        f32x4 acc4[4] = {};
        #pragma unroll
        for (int ks = 0; ks < 2; ++ks)
            #pragma unroll
            for (int n = 0; n < 4; ++n) {
                const int row = n * 16 + lo;
                acc4[n] = MFMA16(aqh[ks],
                    *(const bf16x8*)&kB[row * 64 + (((ks << 2) + hi) ^ (row & 7)) * 8], acc4[n]);
            }

        #pragma unroll
        for (int n = 0; n < 4; ++n) {
            const int mkc = sM[kt * 64 + n * 16 + lo];
            #pragma unroll
            for (int j = 0; j < 4; ++j) {
                const float p = (mqr[j] && mkc) ? __expf(acc4[n][j] * 0.125f) * rinv[j] : 0.f;
                sP32[wid * (16 * 68) + (hi * 4 + j) * 68 + n * 16 + lo] = p;
            }
        }
        asm volatile("s_waitcnt lgkmcnt(0)" ::: "memory");
        __builtin_amdgcn_sched_barrier(0);

        #pragma unroll
        for (int rr = 0; rr < 4; ++rr) {
            const int prow = rr * 4 + hi;
            const f32x4 pv = *(const f32x4*)&sP32[wid * (16 * 68) + prow * 68 + lo * 4];
            __builtin_nontemporal_store(pv,
                (f32x4*)&pattn[((size_t)bh * SEQ + q0 + wid * 16 + prow) * SEQ + kt * 64 + lo * 4]);
        }
        #pragma unroll
        for (int ks = 0; ks < 2; ++ks) {
            const float* pp = &sP32[wid * (16 * 68) + lo * 68 + ks * 32 + hi * 8];
            const f32x4 p0 = *(const f32x4*)pp;
            const f32x4 p1 = *(const f32x4*)(pp + 4);
            bf16x8 ap;
            #pragma unroll
            for (int e = 0; e < 4; ++e) { ap[e] = (short)f2bf(p0[e]); ap[4 + e] = (short)f2bf(p1[e]); }
            #pragma unroll
            for (int n = 0; n < 4; ++n) {
                const int row = n * 16 + lo;
                oacc[n] = MFMA16(ap,
                    *(const bf16x8*)&vB[row * 64 + (((ks << 2) + hi) ^ (row & 7)) * 8], oacc[n]);
            }
        }
        __syncthreads();   // tile kt reads done; tile kt+1 DMA drained
    }

    #pragma unroll
    for (int n = 0; n < 4; ++n)
        #pragma unroll
        for (int j = 0; j < 4; ++j) {
            const int row = q0 + wid * 16 + hi * 4 + j;
            const int col = h * DKH + n * 16 + lo;
            xb[(size_t)(b * SEQ + row) * DMODEL + col] = f2bf(oacc[n][j]);
        }
}

// ---------------------------------------------------------------------------
extern "C" void kernel_launch(void* const* d_in, const int* in_sizes, int n_in,
                              void* d_out, int out_size, void* d_ws, size_t ws_size,
                              hipStream_t stream) {
    (void)in_sizes; (void)n_in; (void)out_size; (void)ws_size;

    const float* query = (const float*)d_in[0];
    const float* key   = (const float*)d_in[1];
    const float* value = (const float*)d_in[2];
    const int*   mask  = (const int*)d_in[3];
    const float* Wq    = (const float*)d_in[4];
    const float* bq    = (const float*)d_in[5];
    const float* Wo    = (const float*)d_in[6];
    const float* bo    = (const float*)d_in[7];

    float* out   = (float*)d_out;                               // (8,1024,1024)
    float* pattn = out + (size_t)NE;                            // (8,16,1024,1024)

    char* w = (char*)d_ws;
    unsigned short* wqhi = (unsigned short*)w;  w += (size_t)WE * 2;
    unsigned short* wohi = (unsigned short*)w;  w += (size_t)WE * 2;
    unsigned short* qhi  = (unsigned short*)w;  w += (size_t)NE * 2;
    unsigned short* khi  = (unsigned short*)w;  w += (size_t)NE * 2;
    unsigned short* vt   = (unsigned short*)w;  w += (size_t)NE * 2;
    unsigned short* xb   = (unsigned short*)w;  w += (size_t)NE * 2;

    cvt_w<<<2 * WE4 / 256, 256, 0, stream>>>(Wq, Wo, wqhi, wohi);

    // fused q/k/v projection (1536 blocks, XCD-chunked 1D swizzle)
    gemm_mfma<3><<<8 * (3 * BATCH * SEQ) / GBM, 256, 0, stream>>>(
        query, key, value, nullptr, wqhi, bq, qhi, vt, nullptr);

    attn_fused<<<BATCH * NHEADS * (SEQ / 128), 512, 0, stream>>>(qhi, khi, vt, mask, pattn, xb);

    // output projection (bf16 x), NT f32 out (512 blocks, same swizzle)
    gemm_mfma<2><<<8 * (BATCH * SEQ) / GBM, 256, 0, stream>>>(
        nullptr, nullptr, nullptr, xb, wohi, bo, nullptr, nullptr, out);
}

// Round 13
// 259.527 us; speedup vs baseline: 1.1556x; 1.1556x over previous
//
#include <hip/hip_runtime.h>
#include <cstddef>
#include <cstdint>

#define BATCH   8
#define SEQ     1024
#define DMODEL  1024
#define NHEADS  16
#define DKH     64
#define NE      (BATCH*SEQ*DMODEL)     // 8388608
#define WE      (DMODEL*DMODEL)        // 1048576
#define WE4     (WE/4)                 // 262144

typedef __attribute__((ext_vector_type(8))) short bf16x8;
typedef __attribute__((ext_vector_type(4))) short s16x4;
typedef __attribute__((ext_vector_type(4))) float f32x4;

#define MFMA16(a,b,c) __builtin_amdgcn_mfma_f32_16x16x32_bf16(a,b,c,0,0,0)

__device__ __forceinline__ unsigned short f2bf(float f) {
    uint32_t u = __float_as_uint(f);
    u += 0x7fffu + ((u >> 16) & 1u);          // round-to-nearest-even
    return (unsigned short)(u >> 16);
}
__device__ __forceinline__ float bf2f(unsigned short s) {
    return __uint_as_float(((uint32_t)s) << 16);
}

// async global->LDS, 16B per lane, dest = wave-uniform base + lane*16
__device__ __forceinline__ void gload16(const void* g, void* l) {
    __builtin_amdgcn_global_load_lds(
        (const __attribute__((address_space(1))) void*)g,
        (__attribute__((address_space(3))) void*)l, 16, 0, 0);
}

// ---------------------------------------------------------------------------
// Weights-only conversion (q/k/v conversion is fused into the proj GEMM).
// ---------------------------------------------------------------------------
__global__ void cvt_w(const float* __restrict__ wq, const float* __restrict__ wo,
                      unsigned short* __restrict__ wqh, unsigned short* __restrict__ woh)
{
    const int i = blockIdx.x * blockDim.x + threadIdx.x;
    const float* src; unsigned short* dst; int j;
    if (i < WE4) { src = wq; dst = wqh; j = i; }
    else         { src = wo; dst = woh; j = i - WE4; }
    const f32x4 x = ((const f32x4*)src)[j];
    s16x4 h4;
    #pragma unroll
    for (int e = 0; e < 4; ++e) h4[e] = (short)f2bf(x[e]);
    ((s16x4*)dst)[j] = h4;
}

// ---------------------------------------------------------------------------
// MFMA GEMM (round-10 verified optimum): 128x128 tile, BK=32, double-buffered
// linear LDS via global_load_lds, ONE barrier per K-step, XCD-chunked swizzle.
// BK=64 variant measured -40us (r12, matches learn_hip m132) — keep BK=32.
// OUTMODE 3: fused q/k/v projection (f32 A converted during reg-staging).
// OUTMODE 2: output projection, f32 out via NON-TEMPORAL stores.
// ---------------------------------------------------------------------------
#define GBM 128
#define GBN 128
#define GBK 32

template<int OUTMODE>
__global__ __launch_bounds__(256, 2)
void gemm_mfma(const float* __restrict__ Aq, const float* __restrict__ Ak,
               const float* __restrict__ Av, const unsigned short* __restrict__ Ab,
               const unsigned short* __restrict__ Whi, const float* __restrict__ bias,
               unsigned short* __restrict__ Ohi, unsigned short* __restrict__ Ovt,
               float* __restrict__ Of)
{
    __shared__ unsigned short sA[2][GBM * GBK];
    __shared__ unsigned short sW[2][GBM * GBK];

    const int tid = threadIdx.x, lane = tid & 63, wid = tid >> 6;
    const int cpx = gridDim.x >> 3;
    const int L = (blockIdx.x & 7) * cpx + (blockIdx.x >> 3);
    const int n0 = (L & 7) * GBN, m0 = (L >> 3) * GBM;
    const int wm = (wid >> 1) * 64, wn = (wid & 1) * 64;
    const int lo = lane & 15, hi4 = lane >> 4;

    const int gs = (lane & 3) ^ ((lane >> 3) & 3);
    const size_t wrow0 = (size_t)(n0 + wid * 32 + (lane >> 2));
    const unsigned short* wSrc0 = &Whi[wrow0 * DMODEL + gs * 8];
    const unsigned short* wSrc1 = &Whi[(wrow0 + 16) * DMODEL + gs * 8];

    const int seg = (OUTMODE == 3) ? (m0 >> 13) : 0;
    const float* Af = (OUTMODE == 3)
        ? (seg == 0 ? Aq : (seg == 1 ? Ak : Av)) : nullptr;
    const int mloc = m0 & 8191;
    const int arow_s = (tid * 2) >> 2;
    const int aslot0 = (tid * 2) & 3;
    const int akey = (arow_s >> 1) & 3;
    const float* aF0 = (OUTMODE == 3) ? &Af[(size_t)(mloc + arow_s) * DMODEL + (aslot0 ^ akey) * 8] : nullptr;
    const float* aF1 = (OUTMODE == 3) ? &Af[(size_t)(mloc + arow_s) * DMODEL + ((aslot0 + 1) ^ akey) * 8] : nullptr;
    const size_t arow0 = (size_t)(m0 + wid * 32 + (lane >> 2));
    const unsigned short* aSrc0 = (OUTMODE == 2) ? &Ab[arow0 * DMODEL + gs * 8] : nullptr;
    const unsigned short* aSrc1 = (OUTMODE == 2) ? &Ab[(arow0 + 16) * DMODEL + gs * 8] : nullptr;

    f32x4 acc[4][4] = {};
    f32x4 ar0, ar1, ar2, ar3;

    if (OUTMODE == 3) {
        ar0 = *(const f32x4*)aF0; ar1 = *(const f32x4*)(aF0 + 4);
        ar2 = *(const f32x4*)aF1; ar3 = *(const f32x4*)(aF1 + 4);
        bf16x8 h0, h1;
        #pragma unroll
        for (int e = 0; e < 4; ++e) {
            h0[e] = (short)f2bf(ar0[e]); h0[4 + e] = (short)f2bf(ar1[e]);
            h1[e] = (short)f2bf(ar2[e]); h1[4 + e] = (short)f2bf(ar3[e]);
        }
        *(bf16x8*)&sA[0][arow_s * GBK + aslot0 * 8]       = h0;
        *(bf16x8*)&sA[0][arow_s * GBK + (aslot0 + 1) * 8] = h1;
    } else {
        unsigned short* dA = &sA[0][(wid * 2) * 512];
        gload16(aSrc0, dA);  gload16(aSrc1, dA + 512);
    }
    {
        unsigned short* dW = &sW[0][(wid * 2) * 512];
        gload16(wSrc0, dW);  gload16(wSrc1, dW + 512);
    }

    for (int kt = 0; kt < DMODEL / GBK; ++kt) {
        __syncthreads();
        const int nb = (kt + 1) & 1;
        if (kt + 1 < DMODEL / GBK) {
            const int kn = (kt + 1) * GBK;
            if (OUTMODE == 3) {
                ar0 = *(const f32x4*)(aF0 + kn); ar1 = *(const f32x4*)(aF0 + kn + 4);
                ar2 = *(const f32x4*)(aF1 + kn); ar3 = *(const f32x4*)(aF1 + kn + 4);
            } else {
                unsigned short* dA = &sA[nb][(wid * 2) * 512];
                gload16(aSrc0 + kn, dA);  gload16(aSrc1 + kn, dA + 512);
            }
            unsigned short* dW = &sW[nb][(wid * 2) * 512];
            gload16(wSrc0 + kn, dW);  gload16(wSrc1 + kn, dW + 512);
        }
        const unsigned short* aB = &sA[kt & 1][0];
        const unsigned short* wB = &sW[kt & 1][0];
        const int swz = (hi4 ^ ((lo >> 1) & 3)) * 8;
        bf16x8 ah[4], bh_[4];
        #pragma unroll
        for (int m = 0; m < 4; ++m)
            ah[m] = *(const bf16x8*)&aB[(wm + m * 16 + lo) * GBK + swz];
        #pragma unroll
        for (int n = 0; n < 4; ++n)
            bh_[n] = *(const bf16x8*)&wB[(wn + n * 16 + lo) * GBK + swz];
        #pragma unroll
        for (int m = 0; m < 4; ++m)
            #pragma unroll
            for (int n = 0; n < 4; ++n)
                acc[m][n] = MFMA16(ah[m], bh_[n], acc[m][n]);

        if (OUTMODE == 3 && kt + 1 < DMODEL / GBK) {
            bf16x8 h0, h1;
            #pragma unroll
            for (int e = 0; e < 4; ++e) {
                h0[e] = (short)f2bf(ar0[e]); h0[4 + e] = (short)f2bf(ar1[e]);
                h1[e] = (short)f2bf(ar2[e]); h1[4 + e] = (short)f2bf(ar3[e]);
            }
            *(bf16x8*)&sA[nb][arow_s * GBK + aslot0 * 8]       = h0;
            *(bf16x8*)&sA[nb][arow_s * GBK + (aslot0 + 1) * 8] = h1;
        }
    }

    #pragma unroll
    for (int n = 0; n < 4; ++n) {
        const int col = n0 + wn + n * 16 + lo;
        const float bv = bias[col];
        #pragma unroll
        for (int m = 0; m < 4; ++m) {
            if (OUTMODE == 3 && seg == 2) {
                const int row0 = (m0 + wm + m * 16 + hi4 * 4) & 8191;
                const int b = row0 >> 10, s0_ = row0 & 1023;
                const int h = col >> 6, di = col & 63;
                s16x4 o;
                #pragma unroll
                for (int j = 0; j < 4; ++j) o[j] = (short)f2bf(acc[m][n][j] + bv);
                *(s16x4*)&Ovt[(((size_t)(b * NHEADS + h)) * DKH + di) * SEQ + s0_] = o;
            } else {
                #pragma unroll
                for (int j = 0; j < 4; ++j) {
                    const int row = m0 + wm + m * 16 + hi4 * 4 + j;
                    const float f = acc[m][n][j] + bv;
                    if (OUTMODE == 3) {
                        const int rs = row & 8191;
                        const int b = rs >> 10, s = rs & 1023;
                        const int h = col >> 6, di = col & 63;
                        unsigned short* dst = Ohi + (size_t)seg * NE;
                        dst[(((size_t)(b * NHEADS + h)) * SEQ + s) * DKH + di] = f2bf(f);
                    } else {
                        __builtin_nontemporal_store(f, &Of[(size_t)row * DMODEL + col]);
                    }
                }
            }
        }
    }
}

// ---------------------------------------------------------------------------
// Fused attention (round-10 verified optimum). Two-pass, 1-term bf16 QK^T,
// fixed-shift softmax. Block = (b,h,128 q-rows), 8 waves, 512 threads,
// LDS 71680 B (2 blocks/CU). K/V staged via global_load_lds DMA
// (pre-swizzled source, slot' = s ^ (row&7), linear LDS dest), double-
// buffered, ONE barrier per K-tile. sP32 aliases dead sQh. NT p-stores.
// r11 (4-buffer pass 1) and r12 restructures measured neutral/negative —
// this version is at its effective floor (~537 MB NT p-write dominated).
// ---------------------------------------------------------------------------
#define ALD 72
#define KTE 4096   // elems per K/V tile buffer (64 rows x 64)

__global__ __launch_bounds__(512, 4)
void attn_fused(const unsigned short* __restrict__ qhi, const unsigned short* __restrict__ khi,
                const unsigned short* __restrict__ vt, const int* __restrict__ mask,
                float* __restrict__ pattn, unsigned short* __restrict__ xb)
{
    __shared__ __align__(16) char smem[71680];
    unsigned short* sQh = (unsigned short*)smem;             // [128*72] (dead after hoist)
    float*          sP32 = (float*)smem;                     // [8][16*68] (pass 2 alias)
    unsigned short* sKh = (unsigned short*)(smem + 34816);   // [2][4096]
    unsigned short* sVt = (unsigned short*)(smem + 51200);   // [2][4096]
    int*            sM  = (int*)(smem + 67584);              // [1024]

    const int blk = blockIdx.x;
    const int idx = blk >> 3;
    const int bh = (blk & 7) * 16 + (idx & 15);
    const int qt = idx >> 4;                   // 0..7
    const int b = bh >> 4, h = bh & 15;
    const int q0 = qt * 128;
    const int tid = threadIdx.x, lane = tid & 63, wid = tid >> 6;
    const int lo = lane & 15, hi = lane >> 4;

    const int sr8 = tid >> 3;
    const int sw  = (tid & 7) ^ (sr8 & 7);
    const unsigned short* kSrc = &khi[(size_t)bh * SEQ * DKH + (size_t)sr8 * DKH + sw * 8];
    const unsigned short* vSrc = &vt[(size_t)bh * DKH * SEQ + (size_t)sr8 * SEQ + sw * 8];

    *(int2*)&sM[tid * 2] = *(const int2*)&mask[b * SEQ + tid * 2];
    #pragma unroll
    for (int c = 0; c < 2; ++c) {
        const int id = tid * 2 + c, row = id >> 3, col = (id & 7) * 8;
        *(bf16x8*)&sQh[row * ALD + col] =
            *(const bf16x8*)&qhi[((size_t)bh * SEQ + q0 + row) * DKH + col];
    }
    gload16(kSrc, &sKh[0] + wid * 512);
    __syncthreads();   // Q staged + K tile0 DMA drained

    const int qrow = wid * 16 + lo;            // 0..127
    bf16x8 aqh[2];
    aqh[0] = *(const bf16x8*)&sQh[qrow * ALD + hi * 8];
    aqh[1] = *(const bf16x8*)&sQh[qrow * ALD + 32 + hi * 8];
    int mqr[4];
    #pragma unroll
    for (int j = 0; j < 4; ++j) mqr[j] = sM[q0 + wid * 16 + hi * 4 + j];

    // ================= PASS 1: row sums =================
    float l4[4] = {0.f, 0.f, 0.f, 0.f};
    for (int kt = 0; kt < 16; ++kt) {
        if (kt < 15)
            gload16(kSrc + (size_t)(kt + 1) * 64 * DKH, &sKh[((kt + 1) & 1) * KTE] + wid * 512);
        const unsigned short* kB = &sKh[(kt & 1) * KTE];
        f32x4 acc4[4] = {};
        #pragma unroll
        for (int ks = 0; ks < 2; ++ks)
            #pragma unroll
            for (int n = 0; n < 4; ++n) {
                const int row = n * 16 + lo;
                acc4[n] = MFMA16(aqh[ks],
                    *(const bf16x8*)&kB[row * 64 + (((ks << 2) + hi) ^ (row & 7)) * 8], acc4[n]);
            }
        #pragma unroll
        for (int n = 0; n < 4; ++n) {
            const int mkc = sM[kt * 64 + n * 16 + lo];
            #pragma unroll
            for (int j = 0; j < 4; ++j)
                l4[j] += (mqr[j] && mkc) ? __expf(acc4[n][j] * 0.125f) : 0.f;
        }
        __syncthreads();   // tile kt reads done; tile kt+1 DMA drained
    }
    float rinv[4];
    #pragma unroll
    for (int j = 0; j < 4; ++j) {
        float s = l4[j];
        #pragma unroll
        for (int o = 1; o < 16; o <<= 1) s += __shfl_xor(s, o, 16);
        rinv[j] = (s > 0.f) ? (1.0f / s) : 0.f;
    }

    // ================= PASS 2: p write + PV =================
    f32x4 oacc[4] = {};
    gload16(kSrc, &sKh[0] + wid * 512);
    gload16(vSrc, &sVt[0] + wid * 512);
    __syncthreads();
    for (int kt = 0; kt < 16; ++kt) {
        if (kt < 15) {
            const int nb = ((kt + 1) & 1);
            gload16(kSrc + (size_t)(kt + 1) * 64 * DKH, &sKh[nb * KTE] + wid * 512);
            gload16(vSrc + (kt + 1) * 64,               &sVt[nb * KTE] + wid * 512);
        }
        const unsigned short* kB = &sKh[(kt & 1) * KTE];
        const unsigned short* vB = &sVt[(kt & 1) * KTE];
        f32x4 acc4[4] = {};
        #pragma unroll
        for (int ks = 0; ks < 2; ++ks)
            #pragma unroll
            for (int n = 0; n < 4; ++n) {
                const int row = n * 16 + lo;
                acc4[n] = MFMA16(aqh[ks],
                    *(const bf16x8*)&kB[row * 64 + (((ks << 2) + hi) ^ (row & 7)) * 8], acc4[n]);
            }

        #pragma unroll
        for (int n = 0; n < 4; ++n) {
            const int mkc = sM[kt * 64 + n * 16 + lo];
            #pragma unroll
            for (int j = 0; j < 4; ++j) {
                const float p = (mqr[j] && mkc) ? __expf(acc4[n][j] * 0.125f) * rinv[j] : 0.f;
                sP32[wid * (16 * 68) + (hi * 4 + j) * 68 + n * 16 + lo] = p;
            }
        }
        asm volatile("s_waitcnt lgkmcnt(0)" ::: "memory");
        __builtin_amdgcn_sched_barrier(0);

        #pragma unroll
        for (int rr = 0; rr < 4; ++rr) {
            const int prow = rr * 4 + hi;
            const f32x4 pv = *(const f32x4*)&sP32[wid * (16 * 68) + prow * 68 + lo * 4];
            __builtin_nontemporal_store(pv,
                (f32x4*)&pattn[((size_t)bh * SEQ + q0 + wid * 16 + prow) * SEQ + kt * 64 + lo * 4]);
        }
        #pragma unroll
        for (int ks = 0; ks < 2; ++ks) {
            const float* pp = &sP32[wid * (16 * 68) + lo * 68 + ks * 32 + hi * 8];
            const f32x4 p0 = *(const f32x4*)pp;
            const f32x4 p1 = *(const f32x4*)(pp + 4);
            bf16x8 ap;
            #pragma unroll
            for (int e = 0; e < 4; ++e) { ap[e] = (short)f2bf(p0[e]); ap[4 + e] = (short)f2bf(p1[e]); }
            #pragma unroll
            for (int n = 0; n < 4; ++n) {
                const int row = n * 16 + lo;
                oacc[n] = MFMA16(ap,
                    *(const bf16x8*)&vB[row * 64 + (((ks << 2) + hi) ^ (row & 7)) * 8], oacc[n]);
            }
        }
        __syncthreads();   // tile kt reads done; tile kt+1 DMA drained
    }

    #pragma unroll
    for (int n = 0; n < 4; ++n)
        #pragma unroll
        for (int j = 0; j < 4; ++j) {
            const int row = q0 + wid * 16 + hi * 4 + j;
            const int col = h * DKH + n * 16 + lo;
            xb[(size_t)(b * SEQ + row) * DMODEL + col] = f2bf(oacc[n][j]);
        }
}

// ---------------------------------------------------------------------------
extern "C" void kernel_launch(void* const* d_in, const int* in_sizes, int n_in,
                              void* d_out, int out_size, void* d_ws, size_t ws_size,
                              hipStream_t stream) {
    (void)in_sizes; (void)n_in; (void)out_size; (void)ws_size;

    const float* query = (const float*)d_in[0];
    const float* key   = (const float*)d_in[1];
    const float* value = (const float*)d_in[2];
    const int*   mask  = (const int*)d_in[3];
    const float* Wq    = (const float*)d_in[4];
    const float* bq    = (const float*)d_in[5];
    const float* Wo    = (const float*)d_in[6];
    const float* bo    = (const float*)d_in[7];

    float* out   = (float*)d_out;                               // (8,1024,1024)
    float* pattn = out + (size_t)NE;                            // (8,16,1024,1024)

    char* w = (char*)d_ws;
    unsigned short* wqhi = (unsigned short*)w;  w += (size_t)WE * 2;
    unsigned short* wohi = (unsigned short*)w;  w += (size_t)WE * 2;
    unsigned short* qhi  = (unsigned short*)w;  w += (size_t)NE * 2;
    unsigned short* khi  = (unsigned short*)w;  w += (size_t)NE * 2;
    unsigned short* vt   = (unsigned short*)w;  w += (size_t)NE * 2;
    unsigned short* xb   = (unsigned short*)w;  w += (size_t)NE * 2;

    cvt_w<<<2 * WE4 / 256, 256, 0, stream>>>(Wq, Wo, wqhi, wohi);

    // fused q/k/v projection (1536 blocks, XCD-chunked 1D swizzle)
    gemm_mfma<3><<<8 * (3 * BATCH * SEQ) / GBM, 256, 0, stream>>>(
        query, key, value, nullptr, wqhi, bq, qhi, vt, nullptr);

    attn_fused<<<BATCH * NHEADS * (SEQ / 128), 512, 0, stream>>>(qhi, khi, vt, mask, pattn, xb);

    // output projection (bf16 x), NT f32 out (512 blocks, same swizzle)
    gemm_mfma<2><<<8 * (BATCH * SEQ) / GBM, 256, 0, stream>>>(
        nullptr, nullptr, nullptr, xb, wohi, bo, nullptr, nullptr, out);
}